// Round 3
// baseline (222.662 us; speedup 1.0000x reference)
//
#include <hip/hip_runtime.h>
#include <hip/hip_bf16.h>
#include <math.h>

#define BB 8
#define TT 256
#define DD 1024
#define HH 512
#define NSPANS 32896   // T*(T+1)/2
#define KK 512
#define NEGV -1e20f
#define NCH 32
#define CHSZ 1028      // NSPANS / NCH
#define NTILE 136      // 16*17/2 span tiles per batch

// ---------------------------------------------------------------------------
// Kernel 1: fused hs = X@Ws + bs ; he = X@We + be   (z = logical half)
// 64x64 tile, K-step 32, double-buffered LDS, reg prefetch, XCD swizzle.
// ---------------------------------------------------------------------------
__global__ __launch_bounds__(256) void gemm_proj(
    const float* __restrict__ X,
    const float* __restrict__ Ws, const float* __restrict__ bs,
    const float* __restrict__ We, const float* __restrict__ be,
    float* __restrict__ hs, float* __restrict__ he)
{
    // XCD-chunked swizzle: 512 blocks -> XCD c owns logical [c*64, c*64+64)
    const int bid = blockIdx.x;
    const int lg  = ((bid & 7) << 6) + (bid >> 3);
    const int z   = lg >> 8;
    const int my  = (lg & 255) >> 3, nx = lg & 7;
    const int m0  = my * 64, n0 = nx * 64;

    const float* __restrict__ W    = z ? We : Ws;
    const float* __restrict__ bias = z ? be : bs;
    float*       __restrict__ Y    = z ? he : hs;

    __shared__ float As[2][32][68];   // [k][m], 16B-aligned rows
    __shared__ float Bs[2][32][64];   // [k][n]

    const int tid = threadIdx.x;
    const int tx = tid & 15, ty = tid >> 4;

    const int kc4 = tid & 7,  mr = tid >> 3;   // A loader: 8 f4-cols x 32 rows
    const int nc4 = tid & 15, kr = tid >> 4;   // B loader: 16 f4-cols x 16 rows

    const float4* X4 = (const float4*)X;
    const float4* W4 = (const float4*)W;

    float4 av0 = X4[((m0 + mr) * DD) / 4 + kc4];
    float4 av1 = X4[((m0 + mr + 32) * DD) / 4 + kc4];
    float4 bv0 = W4[(kr * HH + n0) / 4 + nc4];
    float4 bv1 = W4[((kr + 16) * HH + n0) / 4 + nc4];

    float acc[4][4] = {};

    {
        const float* a0 = (const float*)&av0;
        const float* a1 = (const float*)&av1;
        #pragma unroll
        for (int j = 0; j < 4; ++j) {
            As[0][kc4*4 + j][mr]      = a0[j];
            As[0][kc4*4 + j][mr + 32] = a1[j];
        }
        *(float4*)&Bs[0][kr][nc4*4]      = bv0;
        *(float4*)&Bs[0][kr + 16][nc4*4] = bv1;
    }
    __syncthreads();

    int cur = 0;
    for (int t = 0; t < 32; ++t) {
        if (t < 31) {
            const int k0n = (t + 1) * 32;
            av0 = X4[((m0 + mr) * DD + k0n) / 4 + kc4];
            av1 = X4[((m0 + mr + 32) * DD + k0n) / 4 + kc4];
            bv0 = W4[((k0n + kr) * HH + n0) / 4 + nc4];
            bv1 = W4[((k0n + kr + 16) * HH + n0) / 4 + nc4];
        }
        #pragma unroll 8
        for (int k = 0; k < 32; ++k) {
            const float4 a4 = *(const float4*)&As[cur][k][ty*4];
            const float4 b4 = *(const float4*)&Bs[cur][k][tx*4];
            const float* a = (const float*)&a4;
            const float* b = (const float*)&b4;
            #pragma unroll
            for (int i = 0; i < 4; ++i)
                #pragma unroll
                for (int j = 0; j < 4; ++j)
                    acc[i][j] += a[i] * b[j];
        }
        if (t < 31) {
            const int nb = cur ^ 1;
            const float* a0 = (const float*)&av0;
            const float* a1 = (const float*)&av1;
            #pragma unroll
            for (int j = 0; j < 4; ++j) {
                As[nb][kc4*4 + j][mr]      = a0[j];
                As[nb][kc4*4 + j][mr + 32] = a1[j];
            }
            *(float4*)&Bs[nb][kr][nc4*4]      = bv0;
            *(float4*)&Bs[nb][kr + 16][nc4*4] = bv1;
            __syncthreads();
            cur = nb;
        }
    }

    const float4 bf = *(const float4*)&bias[n0 + tx*4];
    const float* bp = (const float*)&bf;
    #pragma unroll
    for (int i = 0; i < 4; ++i) {
        const int m = m0 + ty*4 + i;
        float4 o;
        o.x = acc[i][0] + bp[0];
        o.y = acc[i][1] + bp[1];
        o.z = acc[i][2] + bp[2];
        o.w = acc[i][3] + bp[3];
        *(float4*)&Y[m * HH + n0 + tx*4] = o;
    }
}

// ---------------------------------------------------------------------------
// Kernel 2: span scores, 16x16 (s,e) tiles, one pair per thread, no shuffles.
// ---------------------------------------------------------------------------
__global__ __launch_bounds__(256) void span_scores(
    const float* __restrict__ hs, const float* __restrict__ he,
    const float* __restrict__ w_score, const float* __restrict__ b_score,
    const int* __restrict__ input_mask, float* __restrict__ scores)
{
    const int bx = blockIdx.x;
    const int b = bx / NTILE;
    int tI = bx - b * NTILE;
    int i = 0, cum = 0;
    while (tI >= cum + (16 - i)) { cum += 16 - i; ++i; }
    const int j = i + (tI - cum);
    const int s0 = i * 16, e0 = j * 16;

    __shared__ float shs[16][516];
    __shared__ float she[16][516];
    __shared__ float sw[512];

    const int tid = threadIdx.x;
    const float4* hs4 = (const float4*)hs;
    const float4* he4 = (const float4*)he;

    for (int idx = tid; idx < 4096; idx += 256) {
        const int row = idx >> 7;      // 0..31
        const int c4  = idx & 127;
        if (row < 16) {
            *(float4*)&shs[row][c4*4] = hs4[((b*TT + s0 + row) * HH) / 4 + c4];
        } else {
            *(float4*)&she[row - 16][c4*4] = he4[((b*TT + e0 + row - 16) * HH) / 4 + c4];
        }
    }
    if (tid < 128) *(float4*)&sw[tid*4] = ((const float4*)w_score)[tid];
    __syncthreads();

    const int ii = tid >> 4, jj = tid & 15;
    const int s = s0 + ii, e = e0 + jj;

    float4 acc4 = make_float4(0.f, 0.f, 0.f, 0.f);
    #pragma unroll 4
    for (int c4 = 0; c4 < 128; ++c4) {
        const float4 a = *(const float4*)&shs[ii][c4*4];
        const float4 v = *(const float4*)&she[jj][c4*4];
        const float4 w = *(const float4*)&sw[c4*4];
        acc4.x += fmaxf(a.x + v.x, 0.f) * w.x;
        acc4.y += fmaxf(a.y + v.y, 0.f) * w.y;
        acc4.z += fmaxf(a.z + v.z, 0.f) * w.z;
        acc4.w += fmaxf(a.w + v.w, 0.f) * w.w;
    }

    if (e >= s) {
        float scv = (acc4.x + acc4.y) + (acc4.z + acc4.w) + b_score[0];
        if (!(input_mask[b*TT + s] && input_mask[b*TT + e])) scv = NEGV;
        scores[b*NSPANS + s*TT - (s*(s-1))/2 + (e - s)] = scv;
    }
}

// ---------------------------------------------------------------------------
// Parallel exact top-K pipeline (12-bit first pass)
// ---------------------------------------------------------------------------
__device__ inline unsigned f2key(float f) {
    unsigned u = __float_as_uint(f);
    return u ^ ((u & 0x80000000u) ? 0xFFFFFFFFu : 0x80000000u);
}

// 3a: per-batch 4096-bin histogram of key>>20 (LDS hist, sparse global merge)
__global__ __launch_bounds__(256) void hist_build(
    const float* __restrict__ scores, unsigned* __restrict__ hist12)
{
    const int b = blockIdx.x >> 5, ch = blockIdx.x & 31;
    const float* sc = scores + b*NSPANS;
    __shared__ unsigned lh[4096];
    const int tid = threadIdx.x;
    for (int i = tid; i < 4096; i += 256) lh[i] = 0;
    __syncthreads();
    const int base = ch*CHSZ;
    for (int i = base + tid; i < base + CHSZ; i += 256)
        atomicAdd(&lh[f2key(sc[i]) >> 20], 1u);
    __syncthreads();
    for (int i = tid; i < 4096; i += 256) {
        const unsigned v = lh[i];
        if (v) atomicAdd(&hist12[b*4096 + i], v);
    }
}

// 3b: find 12-bit prefix bin where cumulative-from-top crosses K
__global__ __launch_bounds__(1024) void find12(
    const unsigned* __restrict__ hist12, unsigned* __restrict__ thrInfo)
{
    const int b = blockIdx.x;
    const unsigned* h = hist12 + b*4096;
    const int tid = threadIdx.x;
    const int lane = tid & 63, wave = tid >> 6;

    const int hi = 4095 - tid*4;
    unsigned psum = h[hi] + h[hi-1] + h[hi-2] + h[hi-3];

    unsigned inc = psum;
    #pragma unroll
    for (int off = 1; off < 64; off <<= 1) {
        unsigned n = __shfl_up(inc, off);
        if (lane >= off) inc += n;
    }
    __shared__ unsigned wsum[16], wpre[16];
    if (lane == 63) wsum[wave] = inc;
    __syncthreads();
    if (tid == 0) { unsigned c = 0; for (int w = 0; w < 16; ++w) { wpre[w] = c; c += wsum[w]; } }
    __syncthreads();

    const unsigned before = wpre[wave] + inc - psum;
    if (before < KK && before + psum >= KK && psum > 0) {
        unsigned cum = before;
        int bin = hi;
        for (int jj = 0; jj < 4; ++jj) {
            const unsigned c = h[hi - jj];
            if (cum + c >= KK) { bin = hi - jj; break; }
            cum += c;
        }
        thrInfo[b*4 + 0] = (unsigned)bin;   // prefix12
        thrInfo[b*4 + 1] = KK - cum;        // remaining within bin
    }
}

// 3c: compact candidates (top-12 == prefix12), keep low 20 bits
__global__ __launch_bounds__(256) void compact_cand(
    const float* __restrict__ scores, const unsigned* __restrict__ thrInfo,
    unsigned* __restrict__ cand, unsigned* __restrict__ candCnt)
{
    const int b = blockIdx.x >> 5, ch = blockIdx.x & 31;
    const float* sc = scores + b*NSPANS;
    const unsigned p12 = thrInfo[b*4 + 0];
    const int base = ch*CHSZ;
    for (int i = base + threadIdx.x; i < base + CHSZ; i += 256) {
        const unsigned key = f2key(sc[i]);
        if ((key >> 20) == p12) {
            const unsigned pos = atomicAdd(&candCnt[b], 1u);
            cand[b*NSPANS + pos] = key & 0xFFFFFu;
        }
    }
}

// 3d: two 10-bit passes -> exact threshold + tiesNeeded
__global__ __launch_bounds__(256) void refine(
    const unsigned* __restrict__ cand, const unsigned* __restrict__ candCnt,
    unsigned* __restrict__ thrInfo)
{
    const int b = blockIdx.x;
    const unsigned* cd = cand + b*NSPANS;
    const unsigned n = candCnt[b];
    const unsigned remaining = thrInfo[b*4 + 1];
    const int tid = threadIdx.x;
    __shared__ unsigned hist[1024];
    __shared__ unsigned sh[2];

    for (int i = tid; i < 1024; i += 256) hist[i] = 0;
    __syncthreads();
    for (unsigned i = tid; i < n; i += 256) atomicAdd(&hist[(cd[i] >> 10) & 1023u], 1u);
    __syncthreads();
    if (tid == 0) {
        unsigned cum = 0; int bin = 1023;
        for (; bin > 0; --bin) { const unsigned c = hist[bin]; if (cum + c >= remaining) break; cum += c; }
        sh[0] = (unsigned)bin; sh[1] = remaining - cum;
    }
    __syncthreads();
    const unsigned b1 = sh[0], rem1 = sh[1];
    __syncthreads();

    for (int i = tid; i < 1024; i += 256) hist[i] = 0;
    __syncthreads();
    for (unsigned i = tid; i < n; i += 256) {
        const unsigned v = cd[i];
        if (((v >> 10) & 1023u) == b1) atomicAdd(&hist[v & 1023u], 1u);
    }
    __syncthreads();
    if (tid == 0) {
        unsigned cum = 0; int bin = 1023;
        for (; bin > 0; --bin) { const unsigned c = hist[bin]; if (cum + c >= rem1) break; cum += c; }
        thrInfo[b*4 + 2] = (thrInfo[b*4 + 0] << 20) | (b1 << 10) | (unsigned)bin;
        thrInfo[b*4 + 3] = rem1 - cum;
    }
}

// 3e: per-chunk counts of (key>thr), (key==thr)
__global__ __launch_bounds__(256) void countGE(
    const float* __restrict__ scores, const unsigned* __restrict__ thrInfo,
    unsigned* __restrict__ chunkCnt)
{
    const int b = blockIdx.x >> 5, ch = blockIdx.x & 31;
    const float* sc = scores + b*NSPANS;
    const unsigned thr = thrInfo[b*4 + 2];
    const int base = ch*CHSZ;
    unsigned g = 0, e = 0;
    for (int i = base + threadIdx.x; i < base + CHSZ; i += 256) {
        const unsigned key = f2key(sc[i]);
        g += (key > thr); e += (key == thr);
    }
    #pragma unroll
    for (int off = 32; off; off >>= 1) { g += __shfl_down(g, off); e += __shfl_down(e, off); }
    __shared__ unsigned sg[4], se[4];
    const int wave = threadIdx.x >> 6, lane = threadIdx.x & 63;
    if (lane == 0) { sg[wave] = g; se[wave] = e; }
    __syncthreads();
    if (threadIdx.x == 0) {
        chunkCnt[(b*NCH + ch)*2 + 0] = sg[0]+sg[1]+sg[2]+sg[3];
        chunkCnt[(b*NCH + ch)*2 + 1] = se[0]+se[1]+se[2]+se[3];
    }
}

// 3f: stable ordered scatter; each block self-computes its chunk base
__global__ __launch_bounds__(256) void scatter(
    const float* __restrict__ scores, const unsigned* __restrict__ thrInfo,
    const unsigned* __restrict__ chunkCnt, int* __restrict__ top_idx)
{
    const int b = blockIdx.x >> 5, ch = blockIdx.x & 31;
    const float* sc = scores + b*NSPANS;
    const unsigned thr = thrInfo[b*4 + 2], ties = thrInfo[b*4 + 3];

    __shared__ unsigned sBase[2];
    if (threadIdx.x == 0) {
        unsigned out = 0, eqp = 0;
        for (int c = 0; c < ch; ++c) {
            const unsigned G = chunkCnt[(b*NCH + c)*2 + 0];
            const unsigned E = chunkCnt[(b*NCH + c)*2 + 1];
            const unsigned room = (eqp >= ties) ? 0u : (ties - eqp);
            out += G + ((E < room) ? E : room);
            eqp += E;
        }
        sBase[0] = out; sBase[1] = eqp;
    }
    __syncthreads();
    unsigned outPos = sBase[0];
    unsigned eqPos  = sBase[1];

    const int tid = threadIdx.x, wave = tid >> 6, lane = tid & 63;
    const unsigned long long lmask = (1ull << lane) - 1ull;
    __shared__ unsigned wS[4], wE[4];

    const int base = ch*CHSZ;
    for (int seg = base; seg < base + CHSZ; seg += 256) {
        const int i = seg + tid;
        const bool valid = (i < base + CHSZ);
        const unsigned key = valid ? f2key(sc[i]) : 0u;
        const bool g  = valid && key > thr;
        const bool eq = valid && key == thr;

        const unsigned long long meq = __ballot(eq);
        if (lane == 0) wE[wave] = (unsigned)__popcll(meq);
        __syncthreads();

        unsigned eqPre = eqPos;
        for (int w = 0; w < wave; ++w) eqPre += wE[w];
        const unsigned myEqRank = eqPre + (unsigned)__popcll(meq & lmask);
        const bool sel = g || (eq && myEqRank < ties);

        const unsigned long long msel = __ballot(sel);
        if (lane == 0) wS[wave] = (unsigned)__popcll(msel);
        __syncthreads();

        unsigned selPre = outPos;
        for (int w = 0; w < wave; ++w) selPre += wS[w];
        if (sel) top_idx[b*KK + selPre + (unsigned)__popcll(msel & lmask)] = i;

        unsigned totS = 0, totE = 0;
        #pragma unroll
        for (int w = 0; w < 4; ++w) { totS += wS[w]; totE += wE[w]; }
        __syncthreads();
        outPos += totS; eqPos += totE;
    }
}

// ---------------------------------------------------------------------------
// Kernel 4: finalize (probs + BCE loss), single block, deterministic
// ---------------------------------------------------------------------------
__global__ __launch_bounds__(1024) void finalize(
    const float* __restrict__ scores, const int* __restrict__ top_idx,
    const int* __restrict__ answer_spans, float* __restrict__ out)
{
    __shared__ int gold[BB*10];
    __shared__ float part[16];
    const int tid = threadIdx.x;

    if (tid < BB*10) {
        const int s0 = answer_spans[tid*2];
        const int e0 = answer_spans[tid*2 + 1];
        gold[tid] = (s0 >= 0) ? ((2*s0*TT - s0*s0 + s0)/2 + (e0 - s0)) : -1;
    }
    __syncthreads();

    float lsum = 0.f;
    for (int t = tid; t < BB*KK; t += 1024) {
        const int b = t >> 9;
        const int idx = top_idx[t];
        const float l = scores[b*NSPANS + idx];
        float prob = 0.f;
        if (l > -1e19f) {
            prob = 1.f / (1.f + expf(-l));
            float pred = 0.f;
            #pragma unroll
            for (int g = 0; g < 10; ++g)
                if (gold[b*10 + g] == idx) pred = 1.f;
            lsum += fmaxf(l, 0.f) - l*pred + log1pf(expf(-fabsf(l)));
        }
        out[t] = prob;
    }

    #pragma unroll
    for (int off = 32; off; off >>= 1) lsum += __shfl_down(lsum, off);
    const int wave = tid >> 6, lane = tid & 63;
    if (lane == 0) part[wave] = lsum;
    __syncthreads();
    if (tid == 0) {
        float ssum = 0.f;
        for (int w = 0; w < 16; ++w) ssum += part[w];
        out[BB*KK] = ssum;
    }
}

// ---------------------------------------------------------------------------
extern "C" void kernel_launch(void* const* d_in, const int* in_sizes, int n_in,
                              void* d_out, int out_size, void* d_ws, size_t ws_size,
                              hipStream_t stream)
{
    const float* inputs       = (const float*)d_in[0];
    const int*   input_mask   = (const int*)  d_in[1];
    const int*   answer_spans = (const int*)  d_in[2];
    const float* W_start      = (const float*)d_in[3];
    const float* b_start      = (const float*)d_in[4];
    const float* W_end        = (const float*)d_in[5];
    const float* b_end        = (const float*)d_in[6];
    const float* w_score      = (const float*)d_in[7];
    const float* b_score      = (const float*)d_in[8];
    float* out = (float*)d_out;
    unsigned* ws = (unsigned*)d_ws;

    // word-offset layout
    float*    hs       = (float*)(ws);                 // 1048576
    float*    he       = (float*)(ws + 1048576);       // 1048576
    float*    scores   = (float*)(ws + 2097152);       // 263168
    int*      top_idx  = (int*)  (ws + 2360320);       // 4096
    unsigned* thrInfo  = ws + 2364416;                 // 32
    unsigned* chunkCnt = ws + 2364448;                 // 512
    unsigned* hist12   = ws + 2364960;                 // 8*4096 = 32768
    unsigned* candCnt  = ws + 2397728;                 // 8 (contiguous after hist12)
    unsigned* cand     = (unsigned*)hs;                // alias, hs dead after span

    gemm_proj<<<512, 256, 0, stream>>>(inputs, W_start, b_start, W_end, b_end, hs, he);
    span_scores<<<BB*NTILE, 256, 0, stream>>>(hs, he, w_score, b_score, input_mask, scores);

    hipMemsetAsync(hist12, 0, (size_t)(BB*4096 + BB)*4, stream);  // hist12 + candCnt

    hist_build  <<<BB*NCH, 256, 0, stream>>>(scores, hist12);
    find12      <<<BB, 1024, 0, stream>>>(hist12, thrInfo);
    compact_cand<<<BB*NCH, 256, 0, stream>>>(scores, thrInfo, cand, candCnt);
    refine      <<<BB, 256, 0, stream>>>(cand, candCnt, thrInfo);
    countGE     <<<BB*NCH, 256, 0, stream>>>(scores, thrInfo, chunkCnt);
    scatter     <<<BB*NCH, 256, 0, stream>>>(scores, thrInfo, chunkCnt, top_idx);

    finalize<<<1, 1024, 0, stream>>>(scores, top_idx, answer_spans, out);
}

// Round 4
// 151.090 us; speedup vs baseline: 1.4737x; 1.4737x over previous
//
#include <hip/hip_runtime.h>
#include <hip/hip_bf16.h>
#include <math.h>

#define BB 8
#define TT 256
#define DD 1024
#define HH 512
#define NSPANS 32896   // T*(T+1)/2
#define KK 512
#define NEGV -1e20f
#define NCH 32
#define CHSZ 1028      // NSPANS / NCH
#define NTILE 136      // 16*17/2 span tiles per batch

// ---------------------------------------------------------------------------
// Kernel 1: fused hs = X@Ws + bs ; he = X@We + be   (z = logical half)
// 64x64 tile, K-step 32, double-buffered LDS, reg prefetch, XCD swizzle.
// ---------------------------------------------------------------------------
__global__ __launch_bounds__(256) void gemm_proj(
    const float* __restrict__ X,
    const float* __restrict__ Ws, const float* __restrict__ bs,
    const float* __restrict__ We, const float* __restrict__ be,
    float* __restrict__ hs, float* __restrict__ he)
{
    const int bid = blockIdx.x;
    const int lg  = ((bid & 7) << 6) + (bid >> 3);
    const int z   = lg >> 8;
    const int my  = (lg & 255) >> 3, nx = lg & 7;
    const int m0  = my * 64, n0 = nx * 64;

    const float* __restrict__ W    = z ? We : Ws;
    const float* __restrict__ bias = z ? be : bs;
    float*       __restrict__ Y    = z ? he : hs;

    __shared__ float As[2][32][68];
    __shared__ float Bs[2][32][64];

    const int tid = threadIdx.x;
    const int tx = tid & 15, ty = tid >> 4;

    const int kc4 = tid & 7,  mr = tid >> 3;
    const int nc4 = tid & 15, kr = tid >> 4;

    const float4* X4 = (const float4*)X;
    const float4* W4 = (const float4*)W;

    float4 av0 = X4[((m0 + mr) * DD) / 4 + kc4];
    float4 av1 = X4[((m0 + mr + 32) * DD) / 4 + kc4];
    float4 bv0 = W4[(kr * HH + n0) / 4 + nc4];
    float4 bv1 = W4[((kr + 16) * HH + n0) / 4 + nc4];

    float acc[4][4] = {};

    {
        const float* a0 = (const float*)&av0;
        const float* a1 = (const float*)&av1;
        #pragma unroll
        for (int j = 0; j < 4; ++j) {
            As[0][kc4*4 + j][mr]      = a0[j];
            As[0][kc4*4 + j][mr + 32] = a1[j];
        }
        *(float4*)&Bs[0][kr][nc4*4]      = bv0;
        *(float4*)&Bs[0][kr + 16][nc4*4] = bv1;
    }
    __syncthreads();

    int cur = 0;
    for (int t = 0; t < 32; ++t) {
        if (t < 31) {
            const int k0n = (t + 1) * 32;
            av0 = X4[((m0 + mr) * DD + k0n) / 4 + kc4];
            av1 = X4[((m0 + mr + 32) * DD + k0n) / 4 + kc4];
            bv0 = W4[((k0n + kr) * HH + n0) / 4 + nc4];
            bv1 = W4[((k0n + kr + 16) * HH + n0) / 4 + nc4];
        }
        #pragma unroll 8
        for (int k = 0; k < 32; ++k) {
            const float4 a4 = *(const float4*)&As[cur][k][ty*4];
            const float4 b4 = *(const float4*)&Bs[cur][k][tx*4];
            const float* a = (const float*)&a4;
            const float* b = (const float*)&b4;
            #pragma unroll
            for (int i = 0; i < 4; ++i)
                #pragma unroll
                for (int j = 0; j < 4; ++j)
                    acc[i][j] += a[i] * b[j];
        }
        if (t < 31) {
            const int nb = cur ^ 1;
            const float* a0 = (const float*)&av0;
            const float* a1 = (const float*)&av1;
            #pragma unroll
            for (int j = 0; j < 4; ++j) {
                As[nb][kc4*4 + j][mr]      = a0[j];
                As[nb][kc4*4 + j][mr + 32] = a1[j];
            }
            *(float4*)&Bs[nb][kr][nc4*4]      = bv0;
            *(float4*)&Bs[nb][kr + 16][nc4*4] = bv1;
            __syncthreads();
            cur = nb;
        }
    }

    const float4 bf = *(const float4*)&bias[n0 + tx*4];
    const float* bp = (const float*)&bf;
    #pragma unroll
    for (int i = 0; i < 4; ++i) {
        const int m = m0 + ty*4 + i;
        float4 o;
        o.x = acc[i][0] + bp[0];
        o.y = acc[i][1] + bp[1];
        o.z = acc[i][2] + bp[2];
        o.w = acc[i][3] + bp[3];
        *(float4*)&Y[m * HH + n0 + tx*4] = o;
    }
}

// ---------------------------------------------------------------------------
// Kernel 2: span scores, 16x16 (s,e) tiles, one pair per thread, no shuffles.
// ---------------------------------------------------------------------------
__global__ __launch_bounds__(256) void span_scores(
    const float* __restrict__ hs, const float* __restrict__ he,
    const float* __restrict__ w_score, const float* __restrict__ b_score,
    const int* __restrict__ input_mask, float* __restrict__ scores)
{
    const int bx = blockIdx.x;
    const int b = bx / NTILE;
    int tI = bx - b * NTILE;
    int i = 0, cum = 0;
    while (tI >= cum + (16 - i)) { cum += 16 - i; ++i; }
    const int j = i + (tI - cum);
    const int s0 = i * 16, e0 = j * 16;

    __shared__ float shs[16][516];
    __shared__ float she[16][516];
    __shared__ float sw[512];

    const int tid = threadIdx.x;
    const float4* hs4 = (const float4*)hs;
    const float4* he4 = (const float4*)he;

    for (int idx = tid; idx < 4096; idx += 256) {
        const int row = idx >> 7;
        const int c4  = idx & 127;
        if (row < 16) {
            *(float4*)&shs[row][c4*4] = hs4[((b*TT + s0 + row) * HH) / 4 + c4];
        } else {
            *(float4*)&she[row - 16][c4*4] = he4[((b*TT + e0 + row - 16) * HH) / 4 + c4];
        }
    }
    if (tid < 128) *(float4*)&sw[tid*4] = ((const float4*)w_score)[tid];
    __syncthreads();

    const int ii = tid >> 4, jj = tid & 15;
    const int s = s0 + ii, e = e0 + jj;

    float4 acc4 = make_float4(0.f, 0.f, 0.f, 0.f);
    #pragma unroll 4
    for (int c4 = 0; c4 < 128; ++c4) {
        const float4 a = *(const float4*)&shs[ii][c4*4];
        const float4 v = *(const float4*)&she[jj][c4*4];
        const float4 w = *(const float4*)&sw[c4*4];
        acc4.x += fmaxf(a.x + v.x, 0.f) * w.x;
        acc4.y += fmaxf(a.y + v.y, 0.f) * w.y;
        acc4.z += fmaxf(a.z + v.z, 0.f) * w.z;
        acc4.w += fmaxf(a.w + v.w, 0.f) * w.w;
    }

    if (e >= s) {
        float scv = (acc4.x + acc4.y) + (acc4.z + acc4.w) + b_score[0];
        if (!(input_mask[b*TT + s] && input_mask[b*TT + e])) scv = NEGV;
        scores[b*NSPANS + s*TT - (s*(s-1))/2 + (e - s)] = scv;
    }
}

// ---------------------------------------------------------------------------
// Parallel exact top-K pipeline (12-bit first pass)
// ---------------------------------------------------------------------------
__device__ inline unsigned f2key(float f) {
    unsigned u = __float_as_uint(f);
    return u ^ ((u & 0x80000000u) ? 0xFFFFFFFFu : 0x80000000u);
}

// 3a: per-batch 4096-bin histogram of key>>20 (LDS hist, sparse global merge)
__global__ __launch_bounds__(256) void hist_build(
    const float* __restrict__ scores, unsigned* __restrict__ hist12)
{
    const int b = blockIdx.x >> 5, ch = blockIdx.x & 31;
    const float* sc = scores + b*NSPANS;
    __shared__ unsigned lh[4096];
    const int tid = threadIdx.x;
    for (int i = tid; i < 4096; i += 256) lh[i] = 0;
    __syncthreads();
    const int base = ch*CHSZ;
    for (int i = base + tid; i < base + CHSZ; i += 256)
        atomicAdd(&lh[f2key(sc[i]) >> 20], 1u);
    __syncthreads();
    for (int i = tid; i < 4096; i += 256) {
        const unsigned v = lh[i];
        if (v) atomicAdd(&hist12[b*4096 + i], v);
    }
}

// 3b: find 12-bit prefix bin where cumulative-from-top crosses K
__global__ __launch_bounds__(1024) void find12(
    const unsigned* __restrict__ hist12, unsigned* __restrict__ thrInfo)
{
    const int b = blockIdx.x;
    const unsigned* h = hist12 + b*4096;
    const int tid = threadIdx.x;
    const int lane = tid & 63, wave = tid >> 6;

    const int hi = 4095 - tid*4;
    unsigned psum = h[hi] + h[hi-1] + h[hi-2] + h[hi-3];

    unsigned inc = psum;
    #pragma unroll
    for (int off = 1; off < 64; off <<= 1) {
        unsigned n = __shfl_up(inc, off);
        if (lane >= off) inc += n;
    }
    __shared__ unsigned wsum[16], wpre[16];
    if (lane == 63) wsum[wave] = inc;
    __syncthreads();
    if (tid == 0) { unsigned c = 0; for (int w = 0; w < 16; ++w) { wpre[w] = c; c += wsum[w]; } }
    __syncthreads();

    const unsigned before = wpre[wave] + inc - psum;
    if (before < KK && before + psum >= KK && psum > 0) {
        unsigned cum = before;
        int bin = hi;
        for (int jj = 0; jj < 4; ++jj) {
            const unsigned c = h[hi - jj];
            if (cum + c >= KK) { bin = hi - jj; break; }
            cum += c;
        }
        thrInfo[b*4 + 0] = (unsigned)bin;   // prefix12
        thrInfo[b*4 + 1] = KK - cum;        // remaining within bin
    }
}

// 3c: compact candidates (top-12 == prefix12), keep low 20 bits
__global__ __launch_bounds__(256) void compact_cand(
    const float* __restrict__ scores, const unsigned* __restrict__ thrInfo,
    unsigned* __restrict__ cand, unsigned* __restrict__ candCnt)
{
    const int b = blockIdx.x >> 5, ch = blockIdx.x & 31;
    const float* sc = scores + b*NSPANS;
    const unsigned p12 = thrInfo[b*4 + 0];
    const int base = ch*CHSZ;
    for (int i = base + threadIdx.x; i < base + CHSZ; i += 256) {
        const unsigned key = f2key(sc[i]);
        if ((key >> 20) == p12) {
            const unsigned pos = atomicAdd(&candCnt[b], 1u);
            cand[b*NSPANS + pos] = key & 0xFFFFFu;
        }
    }
}

// 3d: two 10-bit passes -> exact threshold + tiesNeeded.
// Fully parallel descending-bin scan (1 bin/thread, wave+block scan) —
// replaces the R3 tid==0 serial 1024-iteration dependent-LDS-read loops.
__global__ __launch_bounds__(1024) void refine(
    const unsigned* __restrict__ cand, const unsigned* __restrict__ candCnt,
    unsigned* __restrict__ thrInfo)
{
    const int b = blockIdx.x;
    const unsigned* cd = cand + b*NSPANS;
    const unsigned n = candCnt[b];
    const unsigned remaining = thrInfo[b*4 + 1];
    const int tid = threadIdx.x;
    const int lane = tid & 63, wave = tid >> 6;

    __shared__ unsigned hist[1024];
    __shared__ unsigned wsum[16], wpre[16];
    __shared__ unsigned sh[2];

    // ---- pass 1: bins = (key >> 10) & 1023 ----
    hist[tid] = 0;
    __syncthreads();
    for (unsigned i = tid; i < n; i += 1024) atomicAdd(&hist[(cd[i] >> 10) & 1023u], 1u);
    __syncthreads();

    {
        const unsigned psum = hist[1023 - tid];        // descending-bin order
        unsigned inc = psum;
        #pragma unroll
        for (int off = 1; off < 64; off <<= 1) {
            unsigned v = __shfl_up(inc, off);
            if (lane >= off) inc += v;
        }
        if (lane == 63) wsum[wave] = inc;
        __syncthreads();
        if (tid == 0) { unsigned c = 0; for (int w = 0; w < 16; ++w) { wpre[w] = c; c += wsum[w]; } }
        __syncthreads();
        const unsigned before = wpre[wave] + inc - psum;
        if (before < remaining && before + psum >= remaining && psum > 0) {
            sh[0] = 1023u - (unsigned)tid;     // bin b1
            sh[1] = remaining - before;        // rem1 needed within b1
        }
        __syncthreads();
    }
    const unsigned b1 = sh[0], rem1 = sh[1];
    __syncthreads();

    // ---- pass 2: bins = key & 1023, restricted to b1 ----
    hist[tid] = 0;
    __syncthreads();
    for (unsigned i = tid; i < n; i += 1024) {
        const unsigned v = cd[i];
        if (((v >> 10) & 1023u) == b1) atomicAdd(&hist[v & 1023u], 1u);
    }
    __syncthreads();

    {
        const unsigned psum = hist[1023 - tid];
        unsigned inc = psum;
        #pragma unroll
        for (int off = 1; off < 64; off <<= 1) {
            unsigned v = __shfl_up(inc, off);
            if (lane >= off) inc += v;
        }
        if (lane == 63) wsum[wave] = inc;
        __syncthreads();
        if (tid == 0) { unsigned c = 0; for (int w = 0; w < 16; ++w) { wpre[w] = c; c += wsum[w]; } }
        __syncthreads();
        const unsigned before = wpre[wave] + inc - psum;
        if (before < rem1 && before + psum >= rem1 && psum > 0) {
            const unsigned bin2 = 1023u - (unsigned)tid;
            thrInfo[b*4 + 2] = (thrInfo[b*4 + 0] << 20) | (b1 << 10) | bin2;
            thrInfo[b*4 + 3] = rem1 - before;  // tiesNeeded (count taken at ==thr)
        }
    }
}

// 3e: per-chunk counts of (key>thr), (key==thr)
__global__ __launch_bounds__(256) void countGE(
    const float* __restrict__ scores, const unsigned* __restrict__ thrInfo,
    unsigned* __restrict__ chunkCnt)
{
    const int b = blockIdx.x >> 5, ch = blockIdx.x & 31;
    const float* sc = scores + b*NSPANS;
    const unsigned thr = thrInfo[b*4 + 2];
    const int base = ch*CHSZ;
    unsigned g = 0, e = 0;
    for (int i = base + threadIdx.x; i < base + CHSZ; i += 256) {
        const unsigned key = f2key(sc[i]);
        g += (key > thr); e += (key == thr);
    }
    #pragma unroll
    for (int off = 32; off; off >>= 1) { g += __shfl_down(g, off); e += __shfl_down(e, off); }
    __shared__ unsigned sg[4], se[4];
    const int wave = threadIdx.x >> 6, lane = threadIdx.x & 63;
    if (lane == 0) { sg[wave] = g; se[wave] = e; }
    __syncthreads();
    if (threadIdx.x == 0) {
        chunkCnt[(b*NCH + ch)*2 + 0] = sg[0]+sg[1]+sg[2]+sg[3];
        chunkCnt[(b*NCH + ch)*2 + 1] = se[0]+se[1]+se[2]+se[3];
    }
}

// 3f: stable ordered scatter; each block self-computes its chunk base
__global__ __launch_bounds__(256) void scatter(
    const float* __restrict__ scores, const unsigned* __restrict__ thrInfo,
    const unsigned* __restrict__ chunkCnt, int* __restrict__ top_idx)
{
    const int b = blockIdx.x >> 5, ch = blockIdx.x & 31;
    const float* sc = scores + b*NSPANS;
    const unsigned thr = thrInfo[b*4 + 2], ties = thrInfo[b*4 + 3];

    __shared__ unsigned sBase[2];
    if (threadIdx.x == 0) {
        unsigned out = 0, eqp = 0;
        for (int c = 0; c < ch; ++c) {
            const unsigned G = chunkCnt[(b*NCH + c)*2 + 0];
            const unsigned E = chunkCnt[(b*NCH + c)*2 + 1];
            const unsigned room = (eqp >= ties) ? 0u : (ties - eqp);
            out += G + ((E < room) ? E : room);
            eqp += E;
        }
        sBase[0] = out; sBase[1] = eqp;
    }
    __syncthreads();
    unsigned outPos = sBase[0];
    unsigned eqPos  = sBase[1];

    const int tid = threadIdx.x, wave = tid >> 6, lane = tid & 63;
    const unsigned long long lmask = (1ull << lane) - 1ull;
    __shared__ unsigned wS[4], wE[4];

    const int base = ch*CHSZ;
    for (int seg = base; seg < base + CHSZ; seg += 256) {
        const int i = seg + tid;
        const bool valid = (i < base + CHSZ);
        const unsigned key = valid ? f2key(sc[i]) : 0u;
        const bool g  = valid && key > thr;
        const bool eq = valid && key == thr;

        const unsigned long long meq = __ballot(eq);
        if (lane == 0) wE[wave] = (unsigned)__popcll(meq);
        __syncthreads();

        unsigned eqPre = eqPos;
        for (int w = 0; w < wave; ++w) eqPre += wE[w];
        const unsigned myEqRank = eqPre + (unsigned)__popcll(meq & lmask);
        const bool sel = g || (eq && myEqRank < ties);

        const unsigned long long msel = __ballot(sel);
        if (lane == 0) wS[wave] = (unsigned)__popcll(msel);
        __syncthreads();

        unsigned selPre = outPos;
        for (int w = 0; w < wave; ++w) selPre += wS[w];
        if (sel) top_idx[b*KK + selPre + (unsigned)__popcll(msel & lmask)] = i;

        unsigned totS = 0, totE = 0;
        #pragma unroll
        for (int w = 0; w < 4; ++w) { totS += wS[w]; totE += wE[w]; }
        __syncthreads();
        outPos += totS; eqPos += totE;
    }
}

// ---------------------------------------------------------------------------
// Kernel 4: finalize (probs + BCE loss), single block, deterministic
// ---------------------------------------------------------------------------
__global__ __launch_bounds__(1024) void finalize(
    const float* __restrict__ scores, const int* __restrict__ top_idx,
    const int* __restrict__ answer_spans, float* __restrict__ out)
{
    __shared__ int gold[BB*10];
    __shared__ float part[16];
    const int tid = threadIdx.x;

    if (tid < BB*10) {
        const int s0 = answer_spans[tid*2];
        const int e0 = answer_spans[tid*2 + 1];
        gold[tid] = (s0 >= 0) ? ((2*s0*TT - s0*s0 + s0)/2 + (e0 - s0)) : -1;
    }
    __syncthreads();

    float lsum = 0.f;
    for (int t = tid; t < BB*KK; t += 1024) {
        const int b = t >> 9;
        const int idx = top_idx[t];
        const float l = scores[b*NSPANS + idx];
        float prob = 0.f;
        if (l > -1e19f) {
            prob = 1.f / (1.f + expf(-l));
            float pred = 0.f;
            #pragma unroll
            for (int g = 0; g < 10; ++g)
                if (gold[b*10 + g] == idx) pred = 1.f;
            lsum += fmaxf(l, 0.f) - l*pred + log1pf(expf(-fabsf(l)));
        }
        out[t] = prob;
    }

    #pragma unroll
    for (int off = 32; off; off >>= 1) lsum += __shfl_down(lsum, off);
    const int wave = tid >> 6, lane = tid & 63;
    if (lane == 0) part[wave] = lsum;
    __syncthreads();
    if (tid == 0) {
        float ssum = 0.f;
        for (int w = 0; w < 16; ++w) ssum += part[w];
        out[BB*KK] = ssum;
    }
}

// ---------------------------------------------------------------------------
extern "C" void kernel_launch(void* const* d_in, const int* in_sizes, int n_in,
                              void* d_out, int out_size, void* d_ws, size_t ws_size,
                              hipStream_t stream)
{
    const float* inputs       = (const float*)d_in[0];
    const int*   input_mask   = (const int*)  d_in[1];
    const int*   answer_spans = (const int*)  d_in[2];
    const float* W_start      = (const float*)d_in[3];
    const float* b_start      = (const float*)d_in[4];
    const float* W_end        = (const float*)d_in[5];
    const float* b_end        = (const float*)d_in[6];
    const float* w_score      = (const float*)d_in[7];
    const float* b_score      = (const float*)d_in[8];
    float* out = (float*)d_out;
    unsigned* ws = (unsigned*)d_ws;

    float*    hs       = (float*)(ws);                 // 1048576
    float*    he       = (float*)(ws + 1048576);       // 1048576
    float*    scores   = (float*)(ws + 2097152);       // 263168
    int*      top_idx  = (int*)  (ws + 2360320);       // 4096
    unsigned* thrInfo  = ws + 2364416;                 // 32
    unsigned* chunkCnt = ws + 2364448;                 // 512
    unsigned* hist12   = ws + 2364960;                 // 8*4096 = 32768
    unsigned* candCnt  = ws + 2397728;                 // 8
    unsigned* cand     = (unsigned*)hs;                // alias, hs dead after span

    gemm_proj<<<512, 256, 0, stream>>>(inputs, W_start, b_start, W_end, b_end, hs, he);
    span_scores<<<BB*NTILE, 256, 0, stream>>>(hs, he, w_score, b_score, input_mask, scores);

    hipMemsetAsync(hist12, 0, (size_t)(BB*4096 + BB)*4, stream);  // hist12 + candCnt

    hist_build  <<<BB*NCH, 256, 0, stream>>>(scores, hist12);
    find12      <<<BB, 1024, 0, stream>>>(hist12, thrInfo);
    compact_cand<<<BB*NCH, 256, 0, stream>>>(scores, thrInfo, cand, candCnt);
    refine      <<<BB, 1024, 0, stream>>>(cand, candCnt, thrInfo);
    countGE     <<<BB*NCH, 256, 0, stream>>>(scores, thrInfo, chunkCnt);
    scatter     <<<BB*NCH, 256, 0, stream>>>(scores, thrInfo, chunkCnt, top_idx);

    finalize<<<1, 1024, 0, stream>>>(scores, top_idx, answer_spans, out);
}